// Round 6
// baseline (399.912 us; speedup 1.0000x reference)
//
#include <hip/hip_runtime.h>
#include <math.h>

#define H128 128
#define NF 512  // A*C*H = 2*2*128 features per node
typedef unsigned short u16;

// fp32 -> bf16 round-to-nearest-even
__device__ inline u16 f2bf(float f) {
  union { float f; unsigned u; } x; x.f = f;
  unsigned r = x.u + 0x7FFFu + ((x.u >> 16) & 1u);
  return (u16)(r >> 16);
}
// accumulate 8 bf16 (packed in uint4) into fp32 acc
__device__ inline void addbf8(float* a, uint4 u) {
  a[0] += __uint_as_float(u.x << 16);
  a[1] += __uint_as_float(u.x & 0xFFFF0000u);
  a[2] += __uint_as_float(u.y << 16);
  a[3] += __uint_as_float(u.y & 0xFFFF0000u);
  a[4] += __uint_as_float(u.z << 16);
  a[5] += __uint_as_float(u.z & 0xFFFF0000u);
  a[6] += __uint_as_float(u.w << 16);
  a[7] += __uint_as_float(u.w & 0xFFFF0000u);
}

// ---------------- fused degree count ----------------
__global__ void k_count4(const int* __restrict__ e0s, const int* __restrict__ e0d,
                         const int* __restrict__ e1s, const int* __restrict__ e1d,
                         int E0, int E1,
                         int* __restrict__ c_s0, int* __restrict__ c_d0,
                         int* __restrict__ c_s1, int* __restrict__ c_d1) {
  int i = blockIdx.x * 256 + threadIdx.x;
  if (i < E0) { atomicAdd(&c_s0[e0s[i]], 1); return; }
  i -= E0;
  if (i < E0) { atomicAdd(&c_d0[e0d[i]], 1); return; }
  i -= E0;
  if (i < E1) { atomicAdd(&c_s1[e1s[i]], 1); return; }
  i -= E1;
  if (i < E1) { atomicAdd(&c_d1[e1d[i]], 1); }
}

// ---------------- int degree -> float norm = rsqrt(max(d,1)), in place ----------------
__global__ void k_norm(int* __restrict__ buf, int n) {
  int i = blockIdx.x * 256 + threadIdx.x;
  if (i < n) {
    int d = buf[i];
    float dv = (d < 1) ? 1.0f : (float)d;
    ((float*)buf)[i] = 1.0f / sqrtf(dv);
  }
}

// ---------------- single-pass exclusive scan (1024 thr/block, 2 barriers) ----------------
// Each thread serially handles a contiguous chunk; block-scan of per-thread sums.
__global__ void k_scan2(const int* __restrict__ degA, int nA, int* __restrict__ offA, int* __restrict__ curA,
                        const int* __restrict__ degB, int nB, int* __restrict__ offB, int* __restrict__ curB) {
  const int* deg = blockIdx.x ? degB : degA;
  int n = blockIdx.x ? nB : nA;
  int* off = blockIdx.x ? offB : offA;
  int* cur = blockIdx.x ? curB : curA;
  __shared__ int wsum[16];
  const int tid = threadIdx.x;
  const int lane = tid & 63;
  const int wv = tid >> 6;
  const int per = (n + 1023) >> 10;
  const int base = tid * per;
  int cnt = n - base;
  if (cnt < 0) cnt = 0;
  if (cnt > per) cnt = per;
  int sum = 0;
  for (int i = 0; i < cnt; ++i) sum += deg[base + i];
  // wave inclusive scan of per-thread sums
  int x = sum;
  #pragma unroll
  for (int d2 = 1; d2 < 64; d2 <<= 1) {
    int y = __shfl_up(x, (unsigned)d2, 64);
    if (lane >= d2) x += y;
  }
  if (lane == 63) wsum[wv] = x;
  __syncthreads();
  if (wv == 0 && lane < 16) {
    int w = wsum[lane];
    #pragma unroll
    for (int d2 = 1; d2 < 16; d2 <<= 1) {
      int y = __shfl_up(w, (unsigned)d2, 64);
      if (lane >= d2) w += y;
    }
    wsum[lane] = w;
  }
  __syncthreads();
  int tbase = x - sum + (wv ? wsum[wv - 1] : 0);  // exclusive thread base
  int running = tbase;
  for (int i = 0; i < cnt; ++i) {
    off[base + i] = running;
    cur[base + i] = running;
    running += deg[base + i];
  }
  if (tid == 1023) off[n] = wsum[15];  // grand total
}

// ---------------- fused scatter ----------------
__global__ void k_scatter2(const int* __restrict__ e0s, const int* __restrict__ e0d,
                           const int* __restrict__ e1s, const int* __restrict__ e1d,
                           int E0, int E1,
                           int* __restrict__ cur0, int* __restrict__ csr0,
                           int* __restrict__ cur1, int* __restrict__ csr1) {
  int i = blockIdx.x * 256 + threadIdx.x;
  if (i < E0) {
    int p = atomicAdd(&cur0[e0d[i]], 1);
    csr0[p] = e0s[i];
    return;
  }
  i -= E0;
  if (i < E1) {
    int p = atomicAdd(&cur1[e1d[i]], 1);
    csr1[p] = e1s[i];
  }
}

// ---------------- [A,H,C,N] -> bf16 [N, ac*128+h] * norm[n] ----------------
__global__ __launch_bounds__(256) void k_transpose_in(
    const float* __restrict__ in, const float* __restrict__ norm,
    u16* __restrict__ xp, int N) {
  __shared__ float tile[64][132];  // [n][h], pad 4 keeps b128 alignment
  const int tid = threadIdx.x;
  const int n0 = blockIdx.x << 6;
  const int ac = blockIdx.y;
  const int a = ac >> 1, c = ac & 1;
  const float* base = in + ((size_t)a * 256 + c) * (size_t)N;
  #pragma unroll
  for (int i = 0; i < 8; ++i) {
    int fidx = (i << 8) + tid;
    int h = fidx >> 4;
    int n = (fidx & 15) << 2;
    int gn = n0 + n;
    float4 v = make_float4(0.f, 0.f, 0.f, 0.f);
    if (gn < N) v = *(const float4*)(base + (size_t)h * 2 * N + gn);  // N%4==0
    tile[n + 0][h] = v.x; tile[n + 1][h] = v.y;
    tile[n + 2][h] = v.z; tile[n + 3][h] = v.w;
  }
  __syncthreads();
  #pragma unroll
  for (int i = 0; i < 8; ++i) {
    int fidx = (i << 8) + tid;
    int h4 = fidx & 31;
    int n = fidx >> 5;
    int gn = n0 + n;
    if (gn < N) {
      float4 v = *(const float4*)(&tile[n][h4 << 2]);
      float s = norm[gn];
      ushort4 o;
      o.x = f2bf(v.x * s); o.y = f2bf(v.y * s);
      o.z = f2bf(v.z * s); o.w = f2bf(v.w * s);
      *(ushort4*)(xp + (size_t)gn * NF + ac * H128 + (h4 << 2)) = o;
    }
  }
}

// ---------------- gather-aggregate: wave per dst row, bf16 in, fp32 out ----------------
// Max-TLP design: 16 VGPR, no LDS -> high occupancy; gather is latency/L3-bound.
__global__ __launch_bounds__(256) void k_agg(
    const u16* __restrict__ xp, const int* __restrict__ csr,
    const int* __restrict__ off, const float* __restrict__ norm_dst,
    float* __restrict__ outp, int ndst) {
  const int wave = threadIdx.x >> 6;
  const int lane = threadIdx.x & 63;
  const int d = blockIdx.x * 4 + wave;
  if (d >= ndst) return;
  const int s = off[d], e = off[d + 1];  // wave-uniform
  float acc[8];
  #pragma unroll
  for (int i = 0; i < 8; ++i) acc[i] = 0.f;
  int j = s;
  for (; j + 4 <= e; j += 4) {
    int s0 = csr[j], s1 = csr[j + 1], s2 = csr[j + 2], s3 = csr[j + 3];
    uint4 u0 = *((const uint4*)(xp + (size_t)s0 * NF) + lane);  // 16B/lane, 1KB/row
    uint4 u1 = *((const uint4*)(xp + (size_t)s1 * NF) + lane);
    uint4 u2 = *((const uint4*)(xp + (size_t)s2 * NF) + lane);
    uint4 u3 = *((const uint4*)(xp + (size_t)s3 * NF) + lane);
    addbf8(acc, u0); addbf8(acc, u1); addbf8(acc, u2); addbf8(acc, u3);
  }
  for (; j < e; ++j) {
    uint4 u = *((const uint4*)(xp + (size_t)csr[j] * NF) + lane);
    addbf8(acc, u);
  }
  float nd = norm_dst[d];
  float* orow = outp + (size_t)d * NF + lane * 8;
  *(float4*)orow = make_float4(acc[0] * nd, acc[1] * nd, acc[2] * nd, acc[3] * nd);
  *(float4*)(orow + 4) = make_float4(acc[4] * nd, acc[5] * nd, acc[6] * nd, acc[7] * nd);
}

// ---------------- register-tiled fp32 SGEMM: out = relu(A*W + b) * scale
// A fp32 [M,128]; out fp32 or bf16 per OUT_BF16. BR = 16*RT rows/block.
template <int BR, int RT, bool OUT_BF16>
__global__ __launch_bounds__(256) void k_gemm(
    const float* __restrict__ A, const float* __restrict__ W,
    const float* __restrict__ bias, const float* __restrict__ scale,
    void* __restrict__ outv, int M) {
  __shared__ float As[32][BR + 4];   // [k][row]
  __shared__ float Ws[32][132];      // [k][col]
  const int tid = threadIdx.x;
  const int tx = tid & 15;
  const int ty = tid >> 4;
  const int c0 = tx << 2;
  const int row0 = blockIdx.x * BR;
  float acc[RT][8];
  #pragma unroll
  for (int r = 0; r < RT; ++r)
    #pragma unroll
    for (int c = 0; c < 8; ++c) acc[r][c] = 0.f;

  for (int kc = 0; kc < 128; kc += 32) {
    __syncthreads();
    #pragma unroll
    for (int i = 0; i < 4; ++i) {
      int fidx = (i << 8) + tid;
      int k = fidx >> 5, cq = fidx & 31;
      *(float4*)(&Ws[k][cq << 2]) = *(const float4*)(W + (size_t)(kc + k) * 128 + (cq << 2));
    }
    #pragma unroll
    for (int i = 0; i < BR / 32; ++i) {
      int fidx = (i << 8) + tid;
      int r = fidx >> 3, kq = fidx & 7;
      int row = row0 + r;
      float4 v = make_float4(0.f, 0.f, 0.f, 0.f);
      if (row < M) v = *(const float4*)(A + (size_t)row * 128 + kc + (kq << 2));
      int k = kq << 2;
      As[k + 0][r] = v.x; As[k + 1][r] = v.y;
      As[k + 2][r] = v.z; As[k + 3][r] = v.w;
    }
    __syncthreads();
    #pragma unroll 4
    for (int k = 0; k < 32; ++k) {
      float4 w0 = *(const float4*)(&Ws[k][c0]);
      float4 w1 = *(const float4*)(&Ws[k][64 + c0]);
      float a[RT];
      #pragma unroll
      for (int rr = 0; rr < RT / 4; ++rr) {
        float4 av = *(const float4*)(&As[k][ty * RT + (rr << 2)]);
        a[rr * 4 + 0] = av.x; a[rr * 4 + 1] = av.y;
        a[rr * 4 + 2] = av.z; a[rr * 4 + 3] = av.w;
      }
      #pragma unroll
      for (int r = 0; r < RT; ++r) {
        acc[r][0] = fmaf(a[r], w0.x, acc[r][0]);
        acc[r][1] = fmaf(a[r], w0.y, acc[r][1]);
        acc[r][2] = fmaf(a[r], w0.z, acc[r][2]);
        acc[r][3] = fmaf(a[r], w0.w, acc[r][3]);
        acc[r][4] = fmaf(a[r], w1.x, acc[r][4]);
        acc[r][5] = fmaf(a[r], w1.y, acc[r][5]);
        acc[r][6] = fmaf(a[r], w1.z, acc[r][6]);
        acc[r][7] = fmaf(a[r], w1.w, acc[r][7]);
      }
    }
  }
  float4 b0 = *(const float4*)(bias + c0);
  float4 b1 = *(const float4*)(bias + 64 + c0);
  #pragma unroll
  for (int r = 0; r < RT; ++r) {
    int row = row0 + ty * RT + r;
    if (row < M) {
      float sc = scale ? scale[row >> 2] : 1.f;
      float v[8];
      v[0] = acc[r][0] + b0.x; v[1] = acc[r][1] + b0.y;
      v[2] = acc[r][2] + b0.z; v[3] = acc[r][3] + b0.w;
      v[4] = acc[r][4] + b1.x; v[5] = acc[r][5] + b1.y;
      v[6] = acc[r][6] + b1.z; v[7] = acc[r][7] + b1.w;
      #pragma unroll
      for (int c = 0; c < 8; ++c) v[c] = (v[c] > 0.f ? v[c] : 0.f) * sc;
      if (OUT_BF16) {
        u16* out = (u16*)outv;
        ushort4 q0, q1;
        q0.x = f2bf(v[0]); q0.y = f2bf(v[1]); q0.z = f2bf(v[2]); q0.w = f2bf(v[3]);
        q1.x = f2bf(v[4]); q1.y = f2bf(v[5]); q1.z = f2bf(v[6]); q1.w = f2bf(v[7]);
        *(ushort4*)(out + (size_t)row * 128 + c0) = q0;
        *(ushort4*)(out + (size_t)row * 128 + 64 + c0) = q1;
      } else {
        float* out = (float*)outv;
        *(float4*)(out + (size_t)row * 128 + c0) = make_float4(v[0], v[1], v[2], v[3]);
        *(float4*)(out + (size_t)row * 128 + 64 + c0) = make_float4(v[4], v[5], v[6], v[7]);
      }
    }
  }
}

// ---------------- fp32 [N,512] -> [A,H,C,N] ----------------
__global__ __launch_bounds__(256) void k_transpose_out(
    const float* __restrict__ h1, float* __restrict__ out, int N) {
  __shared__ float tile[128][68];  // [h][n], pad 4
  const int tid = threadIdx.x;
  const int n0 = blockIdx.x << 6;
  const int ac = blockIdx.y;
  const int a = ac >> 1, c = ac & 1;
  #pragma unroll
  for (int i = 0; i < 8; ++i) {
    int fidx = (i << 8) + tid;
    int h4 = fidx & 31;
    int n = fidx >> 5;
    float4 v = *(const float4*)(h1 + (size_t)(n0 + n) * NF + ac * H128 + (h4 << 2));
    int h = h4 << 2;
    tile[h + 0][n] = v.x; tile[h + 1][n] = v.y;
    tile[h + 2][n] = v.z; tile[h + 3][n] = v.w;
  }
  __syncthreads();
  float* obase = out + ((size_t)a * 256 + c) * (size_t)N;
  #pragma unroll
  for (int i = 0; i < 8; ++i) {
    int fidx = (i << 8) + tid;
    int h = fidx >> 4;
    int n = (fidx & 15) << 2;
    float4 v = *(const float4*)(&tile[h][n]);
    *(float4*)(obase + (size_t)h * 2 * N + n0 + n) = v;
  }
}

extern "C" void kernel_launch(void* const* d_in, const int* in_sizes, int n_in,
                              void* d_out, int out_size, void* d_ws, size_t ws_size,
                              hipStream_t stream) {
  const float* in_feat = (const float*)d_in[0];
  const float* W       = (const float*)d_in[1];
  const float* bias    = (const float*)d_in[2];
  const int* e0_src    = (const int*)d_in[3];
  const int* e0_dst    = (const int*)d_in[4];
  const int* e1_src    = (const int*)d_in[5];
  const int* e1_dst    = (const int*)d_in[6];
  const int N_DST0 = 20000;
  const int N_DST1 = 4096;
  const int N_SRC0 = in_sizes[0] / NF;  // 50000
  const int E0 = in_sizes[3];           // 320000
  const int E1 = in_sizes[5];           // 65536

  // ---- workspace layout (fully disjoint; ~132 MB of the scratch) ----
  u16* xp = (u16*)d_ws;                               // bf16 [N_SRC0][512] = 51.2 MB
  u16* h0 = xp + (size_t)N_SRC0 * NF;                 // bf16 [N_DST0][512] = 20.5 MB
  float* agg0 = (float*)(h0 + (size_t)N_DST0 * NF);   // fp32 [N_DST0][512] = 41 MB
  float* agg1 = agg0 + (size_t)N_DST0 * NF;           // fp32 [N_DST1][512] = 8.4 MB
  float* h1   = agg1 + (size_t)N_DST1 * NF;           // fp32 [N_DST1][512] = 8.4 MB
  int* ibase    = (int*)(h1 + (size_t)N_DST1 * NF);
  int* cnt_src0 = ibase;
  int* cnt_dst0 = cnt_src0 + N_SRC0;
  int* cnt_src1 = cnt_dst0 + N_DST0;
  int* cnt_dst1 = cnt_src1 + N_DST0;
  int* off0 = cnt_dst1 + N_DST1;
  int* cur0 = off0 + N_DST0 + 1;
  int* csr0 = cur0 + N_DST0;
  int* off1 = csr0 + E0;
  int* cur1 = off1 + N_DST1 + 1;
  int* csr1 = cur1 + N_DST1;

  const int NCNT = N_SRC0 + N_DST0 + N_DST0 + N_DST1;
  hipMemsetAsync(cnt_src0, 0, (size_t)NCNT * sizeof(int), stream);

  int tot_cnt = 2 * E0 + 2 * E1;
  k_count4<<<(tot_cnt + 255) / 256, 256, 0, stream>>>(
      e0_src, e0_dst, e1_src, e1_dst, E0, E1, cnt_src0, cnt_dst0, cnt_src1, cnt_dst1);

  k_scan2<<<2, 1024, 0, stream>>>(cnt_dst0, N_DST0, off0, cur0,
                                  cnt_dst1, N_DST1, off1, cur1);

  k_norm<<<(NCNT + 255) / 256, 256, 0, stream>>>(cnt_src0, NCNT);

  k_scatter2<<<(E0 + E1 + 255) / 256, 256, 0, stream>>>(
      e0_src, e0_dst, e1_src, e1_dst, E0, E1, cur0, csr0, cur1, csr1);

  dim3 tg1((N_SRC0 + 63) / 64, 4);
  k_transpose_in<<<tg1, 256, 0, stream>>>(in_feat, (const float*)cnt_src0, xp, N_SRC0);

  // layer 0: aggregate (bf16 gather, fp32 out), then GEMM -> bf16 h0
  k_agg<<<(N_DST0 + 3) / 4, 256, 0, stream>>>(
      xp, csr0, off0, (const float*)cnt_dst0, agg0, N_DST0);
  k_gemm<128, 8, true><<<(N_DST0 * 4) / 128, 256, 0, stream>>>(
      agg0, W, bias, (const float*)cnt_src1, (void*)h0, N_DST0 * 4);

  // layer 1: aggregate, GEMM -> fp32 h1
  k_agg<<<(N_DST1 + 3) / 4, 256, 0, stream>>>(
      h0, csr1, off1, (const float*)cnt_dst1, agg1, N_DST1);
  k_gemm<64, 4, false><<<(N_DST1 * 4) / 64, 256, 0, stream>>>(
      agg1, W, bias, nullptr, (void*)h1, N_DST1 * 4);

  dim3 tg2(N_DST1 / 64, 4);
  k_transpose_out<<<tg2, 256, 0, stream>>>(h1, (float*)d_out, N_DST1);
}

// Round 7
// 394.157 us; speedup vs baseline: 1.0146x; 1.0146x over previous
//
#include <hip/hip_runtime.h>
#include <math.h>

#define H128 128
#define NF 512  // A*C*H = 2*2*128 features per node
typedef unsigned short u16;

// fp32 -> bf16 round-to-nearest-even
__device__ inline u16 f2bf(float f) {
  union { float f; unsigned u; } x; x.f = f;
  unsigned r = x.u + 0x7FFFu + ((x.u >> 16) & 1u);
  return (u16)(r >> 16);
}
// accumulate 8 bf16 (packed in uint4) into fp32 acc
__device__ inline void addbf8(float* a, uint4 u) {
  a[0] += __uint_as_float(u.x << 16);
  a[1] += __uint_as_float(u.x & 0xFFFF0000u);
  a[2] += __uint_as_float(u.y << 16);
  a[3] += __uint_as_float(u.y & 0xFFFF0000u);
  a[4] += __uint_as_float(u.z << 16);
  a[5] += __uint_as_float(u.z & 0xFFFF0000u);
  a[6] += __uint_as_float(u.w << 16);
  a[7] += __uint_as_float(u.w & 0xFFFF0000u);
}

// ---------------- fused degree count ----------------
__global__ void k_count4(const int* __restrict__ e0s, const int* __restrict__ e0d,
                         const int* __restrict__ e1s, const int* __restrict__ e1d,
                         int E0, int E1,
                         int* __restrict__ c_s0, int* __restrict__ c_d0,
                         int* __restrict__ c_s1, int* __restrict__ c_d1) {
  int i = blockIdx.x * 256 + threadIdx.x;
  if (i < E0) { atomicAdd(&c_s0[e0s[i]], 1); return; }
  i -= E0;
  if (i < E0) { atomicAdd(&c_d0[e0d[i]], 1); return; }
  i -= E0;
  if (i < E1) { atomicAdd(&c_s1[e1s[i]], 1); return; }
  i -= E1;
  if (i < E1) { atomicAdd(&c_d1[e1d[i]], 1); }
}

// ---------------- int degree -> float norm = rsqrt(max(d,1)), in place ----------------
__global__ void k_norm(int* __restrict__ buf, int n) {
  int i = blockIdx.x * 256 + threadIdx.x;
  if (i < n) {
    int d = buf[i];
    float dv = (d < 1) ? 1.0f : (float)d;
    ((float*)buf)[i] = 1.0f / sqrtf(dv);
  }
}

// ---------------- single-pass exclusive scan (1024 thr/block, 2 barriers) ----------------
__global__ void k_scan2(const int* __restrict__ degA, int nA, int* __restrict__ offA, int* __restrict__ curA,
                        const int* __restrict__ degB, int nB, int* __restrict__ offB, int* __restrict__ curB) {
  const int* deg = blockIdx.x ? degB : degA;
  int n = blockIdx.x ? nB : nA;
  int* off = blockIdx.x ? offB : offA;
  int* cur = blockIdx.x ? curB : curA;
  __shared__ int wsum[16];
  const int tid = threadIdx.x;
  const int lane = tid & 63;
  const int wv = tid >> 6;
  const int per = (n + 1023) >> 10;
  const int base = tid * per;
  int cnt = n - base;
  if (cnt < 0) cnt = 0;
  if (cnt > per) cnt = per;
  int sum = 0;
  for (int i = 0; i < cnt; ++i) sum += deg[base + i];
  int x = sum;
  #pragma unroll
  for (int d2 = 1; d2 < 64; d2 <<= 1) {
    int y = __shfl_up(x, (unsigned)d2, 64);
    if (lane >= d2) x += y;
  }
  if (lane == 63) wsum[wv] = x;
  __syncthreads();
  if (wv == 0 && lane < 16) {
    int w = wsum[lane];
    #pragma unroll
    for (int d2 = 1; d2 < 16; d2 <<= 1) {
      int y = __shfl_up(w, (unsigned)d2, 64);
      if (lane >= d2) w += y;
    }
    wsum[lane] = w;
  }
  __syncthreads();
  int tbase = x - sum + (wv ? wsum[wv - 1] : 0);
  int running = tbase;
  for (int i = 0; i < cnt; ++i) {
    off[base + i] = running;
    cur[base + i] = running;
    running += deg[base + i];
  }
  if (tid == 1023) off[n] = wsum[15];
}

// ---------------- fused scatter ----------------
__global__ void k_scatter2(const int* __restrict__ e0s, const int* __restrict__ e0d,
                           const int* __restrict__ e1s, const int* __restrict__ e1d,
                           int E0, int E1,
                           int* __restrict__ cur0, int* __restrict__ csr0,
                           int* __restrict__ cur1, int* __restrict__ csr1) {
  int i = blockIdx.x * 256 + threadIdx.x;
  if (i < E0) {
    int p = atomicAdd(&cur0[e0d[i]], 1);
    csr0[p] = e0s[i];
    return;
  }
  i -= E0;
  if (i < E1) {
    int p = atomicAdd(&cur1[e1d[i]], 1);
    csr1[p] = e1s[i];
  }
}

// ---------------- [A,H,C,N] -> bf16 [N, ac*128+h] * norm[n] ----------------
// Swizzled LDS: phys(n,h) = n*128 + (((h>>2)+n)&31)*4 + (h&3)
// phase-1 scalar writes: 2-way banks (free); phase-2 b128 reads: conflict-free.
__global__ __launch_bounds__(256) void k_transpose_in(
    const float* __restrict__ in, const float* __restrict__ norm,
    u16* __restrict__ xp, int N) {
  __shared__ float tile[64 * 128];
  const int tid = threadIdx.x;
  const int n0 = blockIdx.x << 6;
  const int ac = blockIdx.y;
  const int a = ac >> 1, c = ac & 1;
  const float* base = in + ((size_t)a * 256 + c) * (size_t)N;
  #pragma unroll
  for (int i = 0; i < 8; ++i) {
    int fidx = (i << 8) + tid;
    int h = fidx >> 4;
    int n = (fidx & 15) << 2;
    int gn = n0 + n;
    float4 v = make_float4(0.f, 0.f, 0.f, 0.f);
    if (gn < N) v = *(const float4*)(base + (size_t)h * 2 * N + gn);  // N%4==0
    int q = h >> 2, rem = h & 3;
    tile[(n + 0) * 128 + (((q + n + 0) & 31) << 2) + rem] = v.x;
    tile[(n + 1) * 128 + (((q + n + 1) & 31) << 2) + rem] = v.y;
    tile[(n + 2) * 128 + (((q + n + 2) & 31) << 2) + rem] = v.z;
    tile[(n + 3) * 128 + (((q + n + 3) & 31) << 2) + rem] = v.w;
  }
  __syncthreads();
  #pragma unroll
  for (int i = 0; i < 8; ++i) {
    int fidx = (i << 8) + tid;
    int h4 = fidx & 31;
    int n = fidx >> 5;
    int gn = n0 + n;
    if (gn < N) {
      float4 v = *(const float4*)(&tile[n * 128 + (((h4 + n) & 31) << 2)]);
      float s = norm[gn];
      ushort4 o;
      o.x = f2bf(v.x * s); o.y = f2bf(v.y * s);
      o.z = f2bf(v.z * s); o.w = f2bf(v.w * s);
      *(ushort4*)(xp + (size_t)gn * NF + ac * H128 + (h4 << 2)) = o;
    }
  }
}

// ---------------- gather-aggregate: wave per dst row, bf16 in, bf16 out ----------------
// Max-TLP design: ~16 VGPR, no LDS -> high occupancy.
__global__ __launch_bounds__(256) void k_agg(
    const u16* __restrict__ xp, const int* __restrict__ csr,
    const int* __restrict__ off, const float* __restrict__ norm_dst,
    u16* __restrict__ outp, int ndst) {
  const int wave = threadIdx.x >> 6;
  const int lane = threadIdx.x & 63;
  const int d = blockIdx.x * 4 + wave;
  if (d >= ndst) return;
  const int s = off[d], e = off[d + 1];  // wave-uniform
  float acc[8];
  #pragma unroll
  for (int i = 0; i < 8; ++i) acc[i] = 0.f;
  int j = s;
  for (; j + 4 <= e; j += 4) {
    int s0 = csr[j], s1 = csr[j + 1], s2 = csr[j + 2], s3 = csr[j + 3];
    uint4 u0 = *((const uint4*)(xp + (size_t)s0 * NF) + lane);  // 16B/lane, 1KB/row
    uint4 u1 = *((const uint4*)(xp + (size_t)s1 * NF) + lane);
    uint4 u2 = *((const uint4*)(xp + (size_t)s2 * NF) + lane);
    uint4 u3 = *((const uint4*)(xp + (size_t)s3 * NF) + lane);
    addbf8(acc, u0); addbf8(acc, u1); addbf8(acc, u2); addbf8(acc, u3);
  }
  for (; j < e; ++j) {
    uint4 u = *((const uint4*)(xp + (size_t)csr[j] * NF) + lane);
    addbf8(acc, u);
  }
  float nd = norm_dst[d];
  u16* orow = outp + (size_t)d * NF + lane * 8;
  ushort4 o0, o1;
  o0.x = f2bf(acc[0] * nd); o0.y = f2bf(acc[1] * nd);
  o0.z = f2bf(acc[2] * nd); o0.w = f2bf(acc[3] * nd);
  o1.x = f2bf(acc[4] * nd); o1.y = f2bf(acc[5] * nd);
  o1.z = f2bf(acc[6] * nd); o1.w = f2bf(acc[7] * nd);
  *(ushort4*)orow = o0;
  *(ushort4*)(orow + 4) = o1;
}

// ---------------- register-tiled fp32 SGEMM, bf16 A: out = relu(A*W + b) * scale
// A bf16 [M,128]; out fp32 or bf16 per OUT_BF16. BR = 16*RT rows/block.
template <int BR, int RT, bool OUT_BF16>
__global__ __launch_bounds__(256) void k_gemm(
    const u16* __restrict__ A, const float* __restrict__ W,
    const float* __restrict__ bias, const float* __restrict__ scale,
    void* __restrict__ outv, int M) {
  __shared__ float As[32][BR + 4];   // [k][row]
  __shared__ float Ws[32][132];      // [k][col]
  const int tid = threadIdx.x;
  const int tx = tid & 15;
  const int ty = tid >> 4;
  const int c0 = tx << 2;
  const int row0 = blockIdx.x * BR;
  float acc[RT][8];
  #pragma unroll
  for (int r = 0; r < RT; ++r)
    #pragma unroll
    for (int c = 0; c < 8; ++c) acc[r][c] = 0.f;

  for (int kc = 0; kc < 128; kc += 32) {
    __syncthreads();
    // stage W chunk [32k x 128c], b128 direct
    #pragma unroll
    for (int i = 0; i < 4; ++i) {
      int fidx = (i << 8) + tid;
      int k = fidx >> 5, cq = fidx & 31;
      *(float4*)(&Ws[k][cq << 2]) = *(const float4*)(W + (size_t)(kc + k) * 128 + (cq << 2));
    }
    // stage A chunk [BR rows x 32k] transposed from bf16: uint4 = 8 bf16 per thread
    #pragma unroll
    for (int i = 0; i < BR / 64; ++i) {
      int fidx = (i << 8) + tid;
      int r = fidx >> 2, c8 = fidx & 3;
      int row = row0 + r;
      uint4 u = make_uint4(0u, 0u, 0u, 0u);
      if (row < M) u = *(const uint4*)(A + (size_t)row * 128 + kc + (c8 << 3));
      int k = c8 << 3;
      As[k + 0][r] = __uint_as_float(u.x << 16);
      As[k + 1][r] = __uint_as_float(u.x & 0xFFFF0000u);
      As[k + 2][r] = __uint_as_float(u.y << 16);
      As[k + 3][r] = __uint_as_float(u.y & 0xFFFF0000u);
      As[k + 4][r] = __uint_as_float(u.z << 16);
      As[k + 5][r] = __uint_as_float(u.z & 0xFFFF0000u);
      As[k + 6][r] = __uint_as_float(u.w << 16);
      As[k + 7][r] = __uint_as_float(u.w & 0xFFFF0000u);
    }
    __syncthreads();
    #pragma unroll 4
    for (int k = 0; k < 32; ++k) {
      float4 w0 = *(const float4*)(&Ws[k][c0]);
      float4 w1 = *(const float4*)(&Ws[k][64 + c0]);
      float a[RT];
      #pragma unroll
      for (int rr = 0; rr < RT / 4; ++rr) {
        float4 av = *(const float4*)(&As[k][ty * RT + (rr << 2)]);
        a[rr * 4 + 0] = av.x; a[rr * 4 + 1] = av.y;
        a[rr * 4 + 2] = av.z; a[rr * 4 + 3] = av.w;
      }
      #pragma unroll
      for (int r = 0; r < RT; ++r) {
        acc[r][0] = fmaf(a[r], w0.x, acc[r][0]);
        acc[r][1] = fmaf(a[r], w0.y, acc[r][1]);
        acc[r][2] = fmaf(a[r], w0.z, acc[r][2]);
        acc[r][3] = fmaf(a[r], w0.w, acc[r][3]);
        acc[r][4] = fmaf(a[r], w1.x, acc[r][4]);
        acc[r][5] = fmaf(a[r], w1.y, acc[r][5]);
        acc[r][6] = fmaf(a[r], w1.z, acc[r][6]);
        acc[r][7] = fmaf(a[r], w1.w, acc[r][7]);
      }
    }
  }
  float4 b0 = *(const float4*)(bias + c0);
  float4 b1 = *(const float4*)(bias + 64 + c0);
  #pragma unroll
  for (int r = 0; r < RT; ++r) {
    int row = row0 + ty * RT + r;
    if (row < M) {
      float sc = scale ? scale[row >> 2] : 1.f;
      float v[8];
      v[0] = acc[r][0] + b0.x; v[1] = acc[r][1] + b0.y;
      v[2] = acc[r][2] + b0.z; v[3] = acc[r][3] + b0.w;
      v[4] = acc[r][4] + b1.x; v[5] = acc[r][5] + b1.y;
      v[6] = acc[r][6] + b1.z; v[7] = acc[r][7] + b1.w;
      #pragma unroll
      for (int c = 0; c < 8; ++c) v[c] = (v[c] > 0.f ? v[c] : 0.f) * sc;
      if (OUT_BF16) {
        u16* out = (u16*)outv;
        ushort4 q0, q1;
        q0.x = f2bf(v[0]); q0.y = f2bf(v[1]); q0.z = f2bf(v[2]); q0.w = f2bf(v[3]);
        q1.x = f2bf(v[4]); q1.y = f2bf(v[5]); q1.z = f2bf(v[6]); q1.w = f2bf(v[7]);
        *(ushort4*)(out + (size_t)row * 128 + c0) = q0;
        *(ushort4*)(out + (size_t)row * 128 + 64 + c0) = q1;
      } else {
        float* out = (float*)outv;
        *(float4*)(out + (size_t)row * 128 + c0) = make_float4(v[0], v[1], v[2], v[3]);
        *(float4*)(out + (size_t)row * 128 + 64 + c0) = make_float4(v[4], v[5], v[6], v[7]);
      }
    }
  }
}

// ---------------- fp32 [N,512] -> [A,H,C,N] ----------------
__global__ __launch_bounds__(256) void k_transpose_out(
    const float* __restrict__ h1, float* __restrict__ out, int N) {
  __shared__ float tile[128][68];  // [h][n], pad 4 (small kernel; conflicts tolerable)
  const int tid = threadIdx.x;
  const int n0 = blockIdx.x << 6;
  const int ac = blockIdx.y;
  const int a = ac >> 1, c = ac & 1;
  #pragma unroll
  for (int i = 0; i < 8; ++i) {
    int fidx = (i << 8) + tid;
    int h4 = fidx & 31;
    int n = fidx >> 5;
    float4 v = *(const float4*)(h1 + (size_t)(n0 + n) * NF + ac * H128 + (h4 << 2));
    int h = h4 << 2;
    tile[h + 0][n] = v.x; tile[h + 1][n] = v.y;
    tile[h + 2][n] = v.z; tile[h + 3][n] = v.w;
  }
  __syncthreads();
  float* obase = out + ((size_t)a * 256 + c) * (size_t)N;
  #pragma unroll
  for (int i = 0; i < 8; ++i) {
    int fidx = (i << 8) + tid;
    int h = fidx >> 4;
    int n = (fidx & 15) << 2;
    float4 v = *(const float4*)(&tile[h][n]);
    *(float4*)(obase + (size_t)h * 2 * N + n0 + n) = v;
  }
}

extern "C" void kernel_launch(void* const* d_in, const int* in_sizes, int n_in,
                              void* d_out, int out_size, void* d_ws, size_t ws_size,
                              hipStream_t stream) {
  const float* in_feat = (const float*)d_in[0];
  const float* W       = (const float*)d_in[1];
  const float* bias    = (const float*)d_in[2];
  const int* e0_src    = (const int*)d_in[3];
  const int* e0_dst    = (const int*)d_in[4];
  const int* e1_src    = (const int*)d_in[5];
  const int* e1_dst    = (const int*)d_in[6];
  const int N_DST0 = 20000;
  const int N_DST1 = 4096;
  const int N_SRC0 = in_sizes[0] / NF;  // 50000
  const int E0 = in_sizes[3];           // 320000
  const int E1 = in_sizes[5];           // 65536

  // ---- workspace layout (fully disjoint) ----
  u16* xp    = (u16*)d_ws;                            // bf16 [N_SRC0][512] = 51.2 MB
  u16* h0    = xp + (size_t)N_SRC0 * NF;              // bf16 [N_DST0][512] = 20.5 MB
  u16* agg0b = h0 + (size_t)N_DST0 * NF;              // bf16 [N_DST0][512] = 20.5 MB
  u16* agg1b = agg0b + (size_t)N_DST0 * NF;           // bf16 [N_DST1][512] = 4.2 MB
  float* h1  = (float*)(agg1b + (size_t)N_DST1 * NF); // fp32 [N_DST1][512] = 8.4 MB
  int* ibase    = (int*)(h1 + (size_t)N_DST1 * NF);
  int* cnt_src0 = ibase;
  int* cnt_dst0 = cnt_src0 + N_SRC0;
  int* cnt_src1 = cnt_dst0 + N_DST0;
  int* cnt_dst1 = cnt_src1 + N_DST0;
  int* off0 = cnt_dst1 + N_DST1;
  int* cur0 = off0 + N_DST0 + 1;
  int* csr0 = cur0 + N_DST0;
  int* off1 = csr0 + E0;
  int* cur1 = off1 + N_DST1 + 1;
  int* csr1 = cur1 + N_DST1;

  const int NCNT = N_SRC0 + N_DST0 + N_DST0 + N_DST1;
  hipMemsetAsync(cnt_src0, 0, (size_t)NCNT * sizeof(int), stream);

  int tot_cnt = 2 * E0 + 2 * E1;
  k_count4<<<(tot_cnt + 255) / 256, 256, 0, stream>>>(
      e0_src, e0_dst, e1_src, e1_dst, E0, E1, cnt_src0, cnt_dst0, cnt_src1, cnt_dst1);

  k_scan2<<<2, 1024, 0, stream>>>(cnt_dst0, N_DST0, off0, cur0,
                                  cnt_dst1, N_DST1, off1, cur1);

  k_norm<<<(NCNT + 255) / 256, 256, 0, stream>>>(cnt_src0, NCNT);

  k_scatter2<<<(E0 + E1 + 255) / 256, 256, 0, stream>>>(
      e0_src, e0_dst, e1_src, e1_dst, E0, E1, cur0, csr0, cur1, csr1);

  dim3 tg1((N_SRC0 + 63) / 64, 4);
  k_transpose_in<<<tg1, 256, 0, stream>>>(in_feat, (const float*)cnt_src0, xp, N_SRC0);

  // layer 0: aggregate (bf16 in/out), then GEMM (bf16 A) -> bf16 h0
  k_agg<<<(N_DST0 + 3) / 4, 256, 0, stream>>>(
      xp, csr0, off0, (const float*)cnt_dst0, agg0b, N_DST0);
  k_gemm<128, 8, true><<<(N_DST0 * 4) / 128, 256, 0, stream>>>(
      agg0b, W, bias, (const float*)cnt_src1, (void*)h0, N_DST0 * 4);

  // layer 1: aggregate, GEMM -> fp32 h1
  k_agg<<<(N_DST1 + 3) / 4, 256, 0, stream>>>(
      h0, csr1, off1, (const float*)cnt_dst1, agg1b, N_DST1);
  k_gemm<64, 4, false><<<(N_DST1 * 4) / 64, 256, 0, stream>>>(
      agg1b, W, bias, nullptr, (void*)h1, N_DST1 * 4);

  dim3 tg2(N_DST1 / 64, 4);
  k_transpose_out<<<tg2, 256, 0, stream>>>(h1, (float*)d_out, N_DST1);
}

// Round 8
// 357.575 us; speedup vs baseline: 1.1184x; 1.1023x over previous
//
#include <hip/hip_runtime.h>
#include <math.h>

#define H128 128
#define NF 512  // A*C*H = 2*2*128 features per node
typedef unsigned short u16;
typedef __attribute__((ext_vector_type(8))) short short8;   // 8 bf16 = 4 VGPRs
typedef __attribute__((ext_vector_type(4))) float floatx4;  // mfma accumulator

// fp32 -> bf16 round-to-nearest-even
__device__ inline u16 f2bf(float f) {
  union { float f; unsigned u; } x; x.f = f;
  unsigned r = x.u + 0x7FFFu + ((x.u >> 16) & 1u);
  return (u16)(r >> 16);
}
// accumulate 8 bf16 (packed in uint4) into fp32 acc
__device__ inline void addbf8(float* a, uint4 u) {
  a[0] += __uint_as_float(u.x << 16);
  a[1] += __uint_as_float(u.x & 0xFFFF0000u);
  a[2] += __uint_as_float(u.y << 16);
  a[3] += __uint_as_float(u.y & 0xFFFF0000u);
  a[4] += __uint_as_float(u.z << 16);
  a[5] += __uint_as_float(u.z & 0xFFFF0000u);
  a[6] += __uint_as_float(u.w << 16);
  a[7] += __uint_as_float(u.w & 0xFFFF0000u);
}

// ---------------- fused degree count ----------------
__global__ void k_count4(const int* __restrict__ e0s, const int* __restrict__ e0d,
                         const int* __restrict__ e1s, const int* __restrict__ e1d,
                         int E0, int E1,
                         int* __restrict__ c_s0, int* __restrict__ c_d0,
                         int* __restrict__ c_s1, int* __restrict__ c_d1) {
  int i = blockIdx.x * 256 + threadIdx.x;
  if (i < E0) { atomicAdd(&c_s0[e0s[i]], 1); return; }
  i -= E0;
  if (i < E0) { atomicAdd(&c_d0[e0d[i]], 1); return; }
  i -= E0;
  if (i < E1) { atomicAdd(&c_s1[e1s[i]], 1); return; }
  i -= E1;
  if (i < E1) { atomicAdd(&c_d1[e1d[i]], 1); }
}

// ---------------- int degree -> float norm = rsqrt(max(d,1)), in place ----------------
__global__ void k_norm(int* __restrict__ buf, int n) {
  int i = blockIdx.x * 256 + threadIdx.x;
  if (i < n) {
    int d = buf[i];
    float dv = (d < 1) ? 1.0f : (float)d;
    ((float*)buf)[i] = 1.0f / sqrtf(dv);
  }
}

// ---------------- single-pass exclusive scan (1024 thr/block, 2 barriers) ----------------
__global__ void k_scan2(const int* __restrict__ degA, int nA, int* __restrict__ offA, int* __restrict__ curA,
                        const int* __restrict__ degB, int nB, int* __restrict__ offB, int* __restrict__ curB) {
  const int* deg = blockIdx.x ? degB : degA;
  int n = blockIdx.x ? nB : nA;
  int* off = blockIdx.x ? offB : offA;
  int* cur = blockIdx.x ? curB : curA;
  __shared__ int wsum[16];
  const int tid = threadIdx.x;
  const int lane = tid & 63;
  const int wv = tid >> 6;
  const int per = (n + 1023) >> 10;
  const int base = tid * per;
  int cnt = n - base;
  if (cnt < 0) cnt = 0;
  if (cnt > per) cnt = per;
  int sum = 0;
  for (int i = 0; i < cnt; ++i) sum += deg[base + i];
  int x = sum;
  #pragma unroll
  for (int d2 = 1; d2 < 64; d2 <<= 1) {
    int y = __shfl_up(x, (unsigned)d2, 64);
    if (lane >= d2) x += y;
  }
  if (lane == 63) wsum[wv] = x;
  __syncthreads();
  if (wv == 0 && lane < 16) {
    int w = wsum[lane];
    #pragma unroll
    for (int d2 = 1; d2 < 16; d2 <<= 1) {
      int y = __shfl_up(w, (unsigned)d2, 64);
      if (lane >= d2) w += y;
    }
    wsum[lane] = w;
  }
  __syncthreads();
  int tbase = x - sum + (wv ? wsum[wv - 1] : 0);
  int running = tbase;
  for (int i = 0; i < cnt; ++i) {
    off[base + i] = running;
    cur[base + i] = running;
    running += deg[base + i];
  }
  if (tid == 1023) off[n] = wsum[15];
}

// ---------------- fused scatter ----------------
__global__ void k_scatter2(const int* __restrict__ e0s, const int* __restrict__ e0d,
                           const int* __restrict__ e1s, const int* __restrict__ e1d,
                           int E0, int E1,
                           int* __restrict__ cur0, int* __restrict__ csr0,
                           int* __restrict__ cur1, int* __restrict__ csr1) {
  int i = blockIdx.x * 256 + threadIdx.x;
  if (i < E0) {
    int p = atomicAdd(&cur0[e0d[i]], 1);
    csr0[p] = e0s[i];
    return;
  }
  i -= E0;
  if (i < E1) {
    int p = atomicAdd(&cur1[e1d[i]], 1);
    csr1[p] = e1s[i];
  }
}

// ---------------- W fp32 [128][128] -> bf16 B-fragment order ----------------
// wfrag[(ct*4+kc)*64 + lane] = 8 bf16: W[kc*32 + (lane>>4)*8 + j][ct*16 + (lane&15)]
__global__ void k_wfrag(const float* __restrict__ W, uint4* __restrict__ wfrag) {
  int t = blockIdx.x * 256 + threadIdx.x;  // 2048 entries total
  int lane = t & 63;
  int pair = t >> 6;                       // ct*4 + kc
  int ct = pair >> 2, kc = pair & 3;
  int quad = lane >> 4, r = lane & 15;
  const float* src = W + (size_t)(kc * 32 + quad * 8) * 128 + ct * 16 + r;
  union { u16 v[8]; uint4 u; } pk;
  #pragma unroll
  for (int j = 0; j < 8; ++j) pk.v[j] = f2bf(src[(size_t)j * 128]);
  wfrag[t] = pk.u;
}

// ---------------- [A,H,C,N] -> bf16 [N, ac*128+h] * norm[n] ----------------
// Swizzled LDS: phys(n,h) = n*128 + (((h>>2)+n)&31)*4 + (h&3)
__global__ __launch_bounds__(256) void k_transpose_in(
    const float* __restrict__ in, const float* __restrict__ norm,
    u16* __restrict__ xp, int N) {
  __shared__ float tile[64 * 128];
  const int tid = threadIdx.x;
  const int n0 = blockIdx.x << 6;
  const int ac = blockIdx.y;
  const int a = ac >> 1, c = ac & 1;
  const float* base = in + ((size_t)a * 256 + c) * (size_t)N;
  #pragma unroll
  for (int i = 0; i < 8; ++i) {
    int fidx = (i << 8) + tid;
    int h = fidx >> 4;
    int n = (fidx & 15) << 2;
    int gn = n0 + n;
    float4 v = make_float4(0.f, 0.f, 0.f, 0.f);
    if (gn < N) v = *(const float4*)(base + (size_t)h * 2 * N + gn);  // N%4==0
    int q = h >> 2, rem = h & 3;
    tile[(n + 0) * 128 + (((q + n + 0) & 31) << 2) + rem] = v.x;
    tile[(n + 1) * 128 + (((q + n + 1) & 31) << 2) + rem] = v.y;
    tile[(n + 2) * 128 + (((q + n + 2) & 31) << 2) + rem] = v.z;
    tile[(n + 3) * 128 + (((q + n + 3) & 31) << 2) + rem] = v.w;
  }
  __syncthreads();
  #pragma unroll
  for (int i = 0; i < 8; ++i) {
    int fidx = (i << 8) + tid;
    int h4 = fidx & 31;
    int n = fidx >> 5;
    int gn = n0 + n;
    if (gn < N) {
      float4 v = *(const float4*)(&tile[n * 128 + (((h4 + n) & 31) << 2)]);
      float s = norm[gn];
      ushort4 o;
      o.x = f2bf(v.x * s); o.y = f2bf(v.y * s);
      o.z = f2bf(v.z * s); o.w = f2bf(v.w * s);
      *(ushort4*)(xp + (size_t)gn * NF + ac * H128 + (h4 << 2)) = o;
    }
  }
}

// ---------------- gather-aggregate: wave per dst row, bf16 in, bf16 out ----------------
__global__ __launch_bounds__(256) void k_agg(
    const u16* __restrict__ xp, const int* __restrict__ csr,
    const int* __restrict__ off, const float* __restrict__ norm_dst,
    u16* __restrict__ outp, int ndst) {
  const int wave = threadIdx.x >> 6;
  const int lane = threadIdx.x & 63;
  const int d = blockIdx.x * 4 + wave;
  if (d >= ndst) return;
  const int s = off[d], e = off[d + 1];  // wave-uniform
  float acc[8];
  #pragma unroll
  for (int i = 0; i < 8; ++i) acc[i] = 0.f;
  int j = s;
  for (; j + 4 <= e; j += 4) {
    int s0 = csr[j], s1 = csr[j + 1], s2 = csr[j + 2], s3 = csr[j + 3];
    uint4 u0 = *((const uint4*)(xp + (size_t)s0 * NF) + lane);  // 16B/lane, 1KB/row
    uint4 u1 = *((const uint4*)(xp + (size_t)s1 * NF) + lane);
    uint4 u2 = *((const uint4*)(xp + (size_t)s2 * NF) + lane);
    uint4 u3 = *((const uint4*)(xp + (size_t)s3 * NF) + lane);
    addbf8(acc, u0); addbf8(acc, u1); addbf8(acc, u2); addbf8(acc, u3);
  }
  for (; j < e; ++j) {
    uint4 u = *((const uint4*)(xp + (size_t)csr[j] * NF) + lane);
    addbf8(acc, u);
  }
  float nd = norm_dst[d];
  u16* orow = outp + (size_t)d * NF + lane * 8;
  ushort4 o0, o1;
  o0.x = f2bf(acc[0] * nd); o0.y = f2bf(acc[1] * nd);
  o0.z = f2bf(acc[2] * nd); o0.w = f2bf(acc[3] * nd);
  o1.x = f2bf(acc[4] * nd); o1.y = f2bf(acc[5] * nd);
  o1.z = f2bf(acc[6] * nd); o1.w = f2bf(acc[7] * nd);
  *(ushort4*)orow = o0;
  *(ushort4*)(orow + 4) = o1;
}

// ---------------- MFMA GEMM: out[M,128] = relu(A[M,128](bf16) * W + b) * scale ----------------
// One wave per 16-row tile; W pre-packed in B-frag order (staged to LDS).
// A-frag: A[m=lane&15][k=quad*8+j]; C/D: row=quad*4+reg, col=lane&15 (m89/m91).
// M must be a multiple of 64.
template <bool OUT_BF16>
__global__ __launch_bounds__(256) void k_gemm_mfma(
    const u16* __restrict__ A, const uint4* __restrict__ wfrag,
    const float* __restrict__ bias, const float* __restrict__ scale,
    void* __restrict__ outv, int M) {
  __shared__ uint4 wb[2048];  // 32 KB
  const int tid = threadIdx.x;
  #pragma unroll
  for (int i = 0; i < 8; ++i) wb[i * 256 + tid] = wfrag[i * 256 + tid];
  __syncthreads();
  const int wave = tid >> 6;
  const int lane = tid & 63;
  const int quad = lane >> 4;
  const int r = lane & 15;
  const int row0 = (blockIdx.x * 4 + wave) << 4;
  if (row0 >= M) return;
  short8 a[4];
  const u16* abase = A + (size_t)(row0 + r) * 128 + quad * 8;
  #pragma unroll
  for (int kc = 0; kc < 4; ++kc) a[kc] = *(const short8*)(abase + kc * 32);
  floatx4 acc[8];
  #pragma unroll
  for (int ct = 0; ct < 8; ++ct) acc[ct] = (floatx4){0.f, 0.f, 0.f, 0.f};
  #pragma unroll
  for (int kc = 0; kc < 4; ++kc) {
    #pragma unroll
    for (int ct = 0; ct < 8; ++ct) {
      short8 b = *(const short8*)&wb[(ct * 4 + kc) * 64 + lane];  // consecutive b128
      acc[ct] = __builtin_amdgcn_mfma_f32_16x16x32_bf16(a[kc], b, acc[ct], 0, 0, 0);
    }
  }
  // epilogue: the 4 regs of a quad are rows of ONE dst node -> scalar scale per quad
  float sc = scale ? scale[(row0 >> 2) + quad] : 1.f;
  #pragma unroll
  for (int ct = 0; ct < 8; ++ct) {
    float bcol = bias[ct * 16 + r];
    #pragma unroll
    for (int reg = 0; reg < 4; ++reg) {
      float v = acc[ct][reg] + bcol;
      v = (v > 0.f ? v : 0.f) * sc;
      size_t idx = (size_t)(row0 + quad * 4 + reg) * 128 + ct * 16 + r;
      if (OUT_BF16) ((u16*)outv)[idx] = f2bf(v);
      else          ((float*)outv)[idx] = v;
    }
  }
}

// ---------------- fp32 [N,512] -> [A,H,C,N] ----------------
__global__ __launch_bounds__(256) void k_transpose_out(
    const float* __restrict__ h1, float* __restrict__ out, int N) {
  __shared__ float tile[128][68];  // [h][n], pad 4
  const int tid = threadIdx.x;
  const int n0 = blockIdx.x << 6;
  const int ac = blockIdx.y;
  const int a = ac >> 1, c = ac & 1;
  #pragma unroll
  for (int i = 0; i < 8; ++i) {
    int fidx = (i << 8) + tid;
    int h4 = fidx & 31;
    int n = fidx >> 5;
    float4 v = *(const float4*)(h1 + (size_t)(n0 + n) * NF + ac * H128 + (h4 << 2));
    int h = h4 << 2;
    tile[h + 0][n] = v.x; tile[h + 1][n] = v.y;
    tile[h + 2][n] = v.z; tile[h + 3][n] = v.w;
  }
  __syncthreads();
  float* obase = out + ((size_t)a * 256 + c) * (size_t)N;
  #pragma unroll
  for (int i = 0; i < 8; ++i) {
    int fidx = (i << 8) + tid;
    int h = fidx >> 4;
    int n = (fidx & 15) << 2;
    float4 v = *(const float4*)(&tile[h][n]);
    *(float4*)(obase + (size_t)h * 2 * N + n0 + n) = v;
  }
}

extern "C" void kernel_launch(void* const* d_in, const int* in_sizes, int n_in,
                              void* d_out, int out_size, void* d_ws, size_t ws_size,
                              hipStream_t stream) {
  const float* in_feat = (const float*)d_in[0];
  const float* W       = (const float*)d_in[1];
  const float* bias    = (const float*)d_in[2];
  const int* e0_src    = (const int*)d_in[3];
  const int* e0_dst    = (const int*)d_in[4];
  const int* e1_src    = (const int*)d_in[5];
  const int* e1_dst    = (const int*)d_in[6];
  const int N_DST0 = 20000;
  const int N_DST1 = 4096;
  const int N_SRC0 = in_sizes[0] / NF;  // 50000
  const int E0 = in_sizes[3];           // 320000
  const int E1 = in_sizes[5];           // 65536

  // ---- workspace layout (fully disjoint) ----
  u16* xp    = (u16*)d_ws;                            // bf16 [N_SRC0][512] = 51.2 MB
  u16* h0    = xp + (size_t)N_SRC0 * NF;              // bf16 [N_DST0][512] = 20.5 MB
  u16* agg0b = h0 + (size_t)N_DST0 * NF;              // bf16 [N_DST0][512] = 20.5 MB
  u16* agg1b = agg0b + (size_t)N_DST0 * NF;           // bf16 [N_DST1][512] = 4.2 MB
  float* h1  = (float*)(agg1b + (size_t)N_DST1 * NF); // fp32 [N_DST1][512] = 8.4 MB
  int* ibase    = (int*)(h1 + (size_t)N_DST1 * NF);
  int* cnt_src0 = ibase;
  int* cnt_dst0 = cnt_src0 + N_SRC0;
  int* cnt_src1 = cnt_dst0 + N_DST0;
  int* cnt_dst1 = cnt_src1 + N_DST0;
  int* off0 = cnt_dst1 + N_DST1;
  int* cur0 = off0 + N_DST0 + 1;
  int* csr0 = cur0 + N_DST0;
  int* off1 = csr0 + E0;
  int* cur1 = off1 + N_DST1 + 1;
  int* csr1 = cur1 + N_DST1;
  uint4* wfrag = (uint4*)(((uintptr_t)(csr1 + E1) + 15) & ~(uintptr_t)15);  // 32 KB

  const int NCNT = N_SRC0 + N_DST0 + N_DST0 + N_DST1;
  hipMemsetAsync(cnt_src0, 0, (size_t)NCNT * sizeof(int), stream);

  int tot_cnt = 2 * E0 + 2 * E1;
  k_count4<<<(tot_cnt + 255) / 256, 256, 0, stream>>>(
      e0_src, e0_dst, e1_src, e1_dst, E0, E1, cnt_src0, cnt_dst0, cnt_src1, cnt_dst1);

  k_scan2<<<2, 1024, 0, stream>>>(cnt_dst0, N_DST0, off0, cur0,
                                  cnt_dst1, N_DST1, off1, cur1);

  k_norm<<<(NCNT + 255) / 256, 256, 0, stream>>>(cnt_src0, NCNT);

  k_scatter2<<<(E0 + E1 + 255) / 256, 256, 0, stream>>>(
      e0_src, e0_dst, e1_src, e1_dst, E0, E1, cur0, csr0, cur1, csr1);

  k_wfrag<<<8, 256, 0, stream>>>(W, wfrag);

  dim3 tg1((N_SRC0 + 63) / 64, 4);
  k_transpose_in<<<tg1, 256, 0, stream>>>(in_feat, (const float*)cnt_src0, xp, N_SRC0);

  // layer 0: aggregate (bf16 in/out), then MFMA GEMM -> bf16 h0
  k_agg<<<(N_DST0 + 3) / 4, 256, 0, stream>>>(
      xp, csr0, off0, (const float*)cnt_dst0, agg0b, N_DST0);
  k_gemm_mfma<true><<<(N_DST0 * 4) / 64, 256, 0, stream>>>(
      agg0b, wfrag, bias, (const float*)cnt_src1, (void*)h0, N_DST0 * 4);

  // layer 1: aggregate, MFMA GEMM -> fp32 h1
  k_agg<<<(N_DST1 + 3) / 4, 256, 0, stream>>>(
      h0, csr1, off1, (const float*)cnt_dst1, agg1b, N_DST1);
  k_gemm_mfma<false><<<(N_DST1 * 4) / 64, 256, 0, stream>>>(
      agg1b, wfrag, bias, nullptr, (void*)h1, N_DST1 * 4);

  dim3 tg2(N_DST1 / 64, 4);
  k_transpose_out<<<tg2, 256, 0, stream>>>(h1, (float*)d_out, N_DST1);
}

// Round 9
// 355.913 us; speedup vs baseline: 1.1236x; 1.0047x over previous
//
#include <hip/hip_runtime.h>
#include <math.h>

#define H128 128
#define NF 512  // A*C*H = 2*2*128 features per node
typedef unsigned short u16;
typedef __attribute__((ext_vector_type(8))) short short8;   // 8 bf16 = 4 VGPRs
typedef __attribute__((ext_vector_type(4))) float floatx4;  // mfma accumulator

// fp32 -> bf16 round-to-nearest-even
__device__ inline u16 f2bf(float f) {
  union { float f; unsigned u; } x; x.f = f;
  unsigned r = x.u + 0x7FFFu + ((x.u >> 16) & 1u);
  return (u16)(r >> 16);
}
// accumulate 8 bf16 (packed in uint4) into fp32 acc
__device__ inline void addbf8(float* a, uint4 u) {
  a[0] += __uint_as_float(u.x << 16);
  a[1] += __uint_as_float(u.x & 0xFFFF0000u);
  a[2] += __uint_as_float(u.y << 16);
  a[3] += __uint_as_float(u.y & 0xFFFF0000u);
  a[4] += __uint_as_float(u.z << 16);
  a[5] += __uint_as_float(u.z & 0xFFFF0000u);
  a[6] += __uint_as_float(u.w << 16);
  a[7] += __uint_as_float(u.w & 0xFFFF0000u);
}

// ---------------- fused degree count ----------------
__global__ void k_count4(const int* __restrict__ e0s, const int* __restrict__ e0d,
                         const int* __restrict__ e1s, const int* __restrict__ e1d,
                         int E0, int E1,
                         int* __restrict__ c_s0, int* __restrict__ c_d0,
                         int* __restrict__ c_s1, int* __restrict__ c_d1) {
  int i = blockIdx.x * 256 + threadIdx.x;
  if (i < E0) { atomicAdd(&c_s0[e0s[i]], 1); return; }
  i -= E0;
  if (i < E0) { atomicAdd(&c_d0[e0d[i]], 1); return; }
  i -= E0;
  if (i < E1) { atomicAdd(&c_s1[e1s[i]], 1); return; }
  i -= E1;
  if (i < E1) { atomicAdd(&c_d1[e1d[i]], 1); }
}

// ---------------- int degree -> float norm = rsqrt(max(d,1)), in place ----------------
__global__ void k_norm(int* __restrict__ buf, int n) {
  int i = blockIdx.x * 256 + threadIdx.x;
  if (i < n) {
    int d = buf[i];
    float dv = (d < 1) ? 1.0f : (float)d;
    ((float*)buf)[i] = 1.0f / sqrtf(dv);
  }
}

// ---------------- single-pass exclusive scan (1024 thr/block, 2 barriers) ----------------
__global__ void k_scan2(const int* __restrict__ degA, int nA, int* __restrict__ offA, int* __restrict__ curA,
                        const int* __restrict__ degB, int nB, int* __restrict__ offB, int* __restrict__ curB) {
  const int* deg = blockIdx.x ? degB : degA;
  int n = blockIdx.x ? nB : nA;
  int* off = blockIdx.x ? offB : offA;
  int* cur = blockIdx.x ? curB : curA;
  __shared__ int wsum[16];
  const int tid = threadIdx.x;
  const int lane = tid & 63;
  const int wv = tid >> 6;
  const int per = (n + 1023) >> 10;
  const int base = tid * per;
  int cnt = n - base;
  if (cnt < 0) cnt = 0;
  if (cnt > per) cnt = per;
  int sum = 0;
  for (int i = 0; i < cnt; ++i) sum += deg[base + i];
  int x = sum;
  #pragma unroll
  for (int d2 = 1; d2 < 64; d2 <<= 1) {
    int y = __shfl_up(x, (unsigned)d2, 64);
    if (lane >= d2) x += y;
  }
  if (lane == 63) wsum[wv] = x;
  __syncthreads();
  if (wv == 0 && lane < 16) {
    int w = wsum[lane];
    #pragma unroll
    for (int d2 = 1; d2 < 16; d2 <<= 1) {
      int y = __shfl_up(w, (unsigned)d2, 64);
      if (lane >= d2) w += y;
    }
    wsum[lane] = w;
  }
  __syncthreads();
  int tbase = x - sum + (wv ? wsum[wv - 1] : 0);
  int running = tbase;
  for (int i = 0; i < cnt; ++i) {
    off[base + i] = running;
    cur[base + i] = running;
    running += deg[base + i];
  }
  if (tid == 1023) off[n] = wsum[15];
}

// ---------------- fused scatter ----------------
__global__ void k_scatter2(const int* __restrict__ e0s, const int* __restrict__ e0d,
                           const int* __restrict__ e1s, const int* __restrict__ e1d,
                           int E0, int E1,
                           int* __restrict__ cur0, int* __restrict__ csr0,
                           int* __restrict__ cur1, int* __restrict__ csr1) {
  int i = blockIdx.x * 256 + threadIdx.x;
  if (i < E0) {
    int p = atomicAdd(&cur0[e0d[i]], 1);
    csr0[p] = e0s[i];
    return;
  }
  i -= E0;
  if (i < E1) {
    int p = atomicAdd(&cur1[e1d[i]], 1);
    csr1[p] = e1s[i];
  }
}

// ---------------- W fp32 [128][128] -> bf16 B-fragment order ----------------
// wfrag[(ct*4+kc)*64 + lane] = 8 bf16: W[kc*32 + (lane>>4)*8 + j][ct*16 + (lane&15)]
__global__ void k_wfrag(const float* __restrict__ W, uint4* __restrict__ wfrag) {
  int t = blockIdx.x * 256 + threadIdx.x;  // 2048 entries total
  int lane = t & 63;
  int pair = t >> 6;                       // ct*4 + kc
  int ct = pair >> 2, kc = pair & 3;
  int quad = lane >> 4, r = lane & 15;
  const float* src = W + (size_t)(kc * 32 + quad * 8) * 128 + ct * 16 + r;
  union { u16 v[8]; uint4 u; } pk;
  #pragma unroll
  for (int j = 0; j < 8; ++j) pk.v[j] = f2bf(src[(size_t)j * 128]);
  wfrag[t] = pk.u;
}

// ---------------- [A,H,C,N] -> bf16 [N, ac*128+h] * norm[n] ----------------
// Swizzled LDS: phys(n,h) = n*128 + (((h>>2) + (n>>2)) & 31)*4 + (h&3)
// phase-1 scalar writes: banks ((q+t) mod 8)*4+rem over 16-lane groups -> 2-way
// across the wave (free, m136); phase-2 b128 reads: all 32 quads distinct.
__global__ __launch_bounds__(256) void k_transpose_in(
    const float* __restrict__ in, const float* __restrict__ norm,
    u16* __restrict__ xp, int N) {
  __shared__ float tile[64 * 128];
  const int tid = threadIdx.x;
  const int n0 = blockIdx.x << 6;
  const int ac = blockIdx.y;
  const int a = ac >> 1, c = ac & 1;
  const float* base = in + ((size_t)a * 256 + c) * (size_t)N;
  #pragma unroll
  for (int i = 0; i < 8; ++i) {
    int fidx = (i << 8) + tid;
    int h = fidx >> 4;
    int t = fidx & 15;
    int n = t << 2;
    int gn = n0 + n;
    float4 v = make_float4(0.f, 0.f, 0.f, 0.f);
    if (gn < N) v = *(const float4*)(base + (size_t)h * 2 * N + gn);  // N%4==0
    int q = h >> 2, rem = h & 3;
    int rot = ((q + t) & 31) << 2;  // (n+j)>>2 == t for j=0..3
    tile[(n + 0) * 128 + rot + rem] = v.x;
    tile[(n + 1) * 128 + rot + rem] = v.y;
    tile[(n + 2) * 128 + rot + rem] = v.z;
    tile[(n + 3) * 128 + rot + rem] = v.w;
  }
  __syncthreads();
  #pragma unroll
  for (int i = 0; i < 8; ++i) {
    int fidx = (i << 8) + tid;
    int h4 = fidx & 31;
    int n = fidx >> 5;
    int gn = n0 + n;
    if (gn < N) {
      float4 v = *(const float4*)(&tile[n * 128 + (((h4 + (n >> 2)) & 31) << 2)]);
      float s = norm[gn];
      ushort4 o;
      o.x = f2bf(v.x * s); o.y = f2bf(v.y * s);
      o.z = f2bf(v.z * s); o.w = f2bf(v.w * s);
      *(ushort4*)(xp + (size_t)gn * NF + ac * H128 + (h4 << 2)) = o;
    }
  }
}

// ---------------- gather-aggregate: wave per dst row, bf16 in, bf16 out ----------------
__global__ __launch_bounds__(256) void k_agg(
    const u16* __restrict__ xp, const int* __restrict__ csr,
    const int* __restrict__ off, const float* __restrict__ norm_dst,
    u16* __restrict__ outp, int ndst) {
  const int wave = threadIdx.x >> 6;
  const int lane = threadIdx.x & 63;
  const int d = blockIdx.x * 4 + wave;
  if (d >= ndst) return;
  const int s = off[d], e = off[d + 1];  // wave-uniform
  float acc[8];
  #pragma unroll
  for (int i = 0; i < 8; ++i) acc[i] = 0.f;
  int j = s;
  for (; j + 4 <= e; j += 4) {
    int s0 = csr[j], s1 = csr[j + 1], s2 = csr[j + 2], s3 = csr[j + 3];
    uint4 u0 = *((const uint4*)(xp + (size_t)s0 * NF) + lane);  // 16B/lane, 1KB/row
    uint4 u1 = *((const uint4*)(xp + (size_t)s1 * NF) + lane);
    uint4 u2 = *((const uint4*)(xp + (size_t)s2 * NF) + lane);
    uint4 u3 = *((const uint4*)(xp + (size_t)s3 * NF) + lane);
    addbf8(acc, u0); addbf8(acc, u1); addbf8(acc, u2); addbf8(acc, u3);
  }
  for (; j < e; ++j) {
    uint4 u = *((const uint4*)(xp + (size_t)csr[j] * NF) + lane);
    addbf8(acc, u);
  }
  float nd = norm_dst[d];
  u16* orow = outp + (size_t)d * NF + lane * 8;
  ushort4 o0, o1;
  o0.x = f2bf(acc[0] * nd); o0.y = f2bf(acc[1] * nd);
  o0.z = f2bf(acc[2] * nd); o0.w = f2bf(acc[3] * nd);
  o1.x = f2bf(acc[4] * nd); o1.y = f2bf(acc[5] * nd);
  o1.z = f2bf(acc[6] * nd); o1.w = f2bf(acc[7] * nd);
  *(ushort4*)orow = o0;
  *(ushort4*)(orow + 4) = o1;
}

// ---------------- MFMA GEMM: out[M,128] = relu(A[M,128](bf16) * W + b) * scale ----------------
// One wave per 16-row tile; W pre-packed in B-frag order (staged to LDS).
// A-frag: A[m=lane&15][k=quad*8+j]; C/D: row=quad*4+reg, col=lane&15 (m89/m91).
// M must be a multiple of 64.
template <bool OUT_BF16>
__global__ __launch_bounds__(256) void k_gemm_mfma(
    const u16* __restrict__ A, const uint4* __restrict__ wfrag,
    const float* __restrict__ bias, const float* __restrict__ scale,
    void* __restrict__ outv, int M) {
  __shared__ uint4 wb[2048];  // 32 KB
  const int tid = threadIdx.x;
  #pragma unroll
  for (int i = 0; i < 8; ++i) wb[i * 256 + tid] = wfrag[i * 256 + tid];
  __syncthreads();
  const int wave = tid >> 6;
  const int lane = tid & 63;
  const int quad = lane >> 4;
  const int r = lane & 15;
  const int row0 = (blockIdx.x * 4 + wave) << 4;
  if (row0 >= M) return;
  short8 a[4];
  const u16* abase = A + (size_t)(row0 + r) * 128 + quad * 8;
  #pragma unroll
  for (int kc = 0; kc < 4; ++kc) a[kc] = *(const short8*)(abase + kc * 32);
  floatx4 acc[8];
  #pragma unroll
  for (int ct = 0; ct < 8; ++ct) acc[ct] = (floatx4){0.f, 0.f, 0.f, 0.f};
  #pragma unroll
  for (int kc = 0; kc < 4; ++kc) {
    #pragma unroll
    for (int ct = 0; ct < 8; ++ct) {
      short8 b = *(const short8*)&wb[(ct * 4 + kc) * 64 + lane];  // consecutive b128
      acc[ct] = __builtin_amdgcn_mfma_f32_16x16x32_bf16(a[kc], b, acc[ct], 0, 0, 0);
    }
  }
  // epilogue: the 4 regs of a quad are rows of ONE dst node -> scalar scale per quad
  float sc = scale ? scale[(row0 >> 2) + quad] : 1.f;
  #pragma unroll
  for (int ct = 0; ct < 8; ++ct) {
    float bcol = bias[ct * 16 + r];
    #pragma unroll
    for (int reg = 0; reg < 4; ++reg) {
      float v = acc[ct][reg] + bcol;
      v = (v > 0.f ? v : 0.f) * sc;
      size_t idx = (size_t)(row0 + quad * 4 + reg) * 128 + ct * 16 + r;
      if (OUT_BF16) ((u16*)outv)[idx] = f2bf(v);
      else          ((float*)outv)[idx] = v;
    }
  }
}

// ---------------- fp32 [N,512] -> [A,H,C,N] ----------------
__global__ __launch_bounds__(256) void k_transpose_out(
    const float* __restrict__ h1, float* __restrict__ out, int N) {
  __shared__ float tile[128][68];  // [h][n], pad 4
  const int tid = threadIdx.x;
  const int n0 = blockIdx.x << 6;
  const int ac = blockIdx.y;
  const int a = ac >> 1, c = ac & 1;
  #pragma unroll
  for (int i = 0; i < 8; ++i) {
    int fidx = (i << 8) + tid;
    int h4 = fidx & 31;
    int n = fidx >> 5;
    float4 v = *(const float4*)(h1 + (size_t)(n0 + n) * NF + ac * H128 + (h4 << 2));
    int h = h4 << 2;
    tile[h + 0][n] = v.x; tile[h + 1][n] = v.y;
    tile[h + 2][n] = v.z; tile[h + 3][n] = v.w;
  }
  __syncthreads();
  float* obase = out + ((size_t)a * 256 + c) * (size_t)N;
  #pragma unroll
  for (int i = 0; i < 8; ++i) {
    int fidx = (i << 8) + tid;
    int h = fidx >> 4;
    int n = (fidx & 15) << 2;
    float4 v = *(const float4*)(&tile[h][n]);
    *(float4*)(obase + (size_t)h * 2 * N + n0 + n) = v;
  }
}

extern "C" void kernel_launch(void* const* d_in, const int* in_sizes, int n_in,
                              void* d_out, int out_size, void* d_ws, size_t ws_size,
                              hipStream_t stream) {
  const float* in_feat = (const float*)d_in[0];
  const float* W       = (const float*)d_in[1];
  const float* bias    = (const float*)d_in[2];
  const int* e0_src    = (const int*)d_in[3];
  const int* e0_dst    = (const int*)d_in[4];
  const int* e1_src    = (const int*)d_in[5];
  const int* e1_dst    = (const int*)d_in[6];
  const int N_DST0 = 20000;
  const int N_DST1 = 4096;
  const int N_SRC0 = in_sizes[0] / NF;  // 50000
  const int E0 = in_sizes[3];           // 320000
  const int E1 = in_sizes[5];           // 65536

  // ---- workspace layout (fully disjoint) ----
  u16* xp    = (u16*)d_ws;                            // bf16 [N_SRC0][512] = 51.2 MB
  u16* h0    = xp + (size_t)N_SRC0 * NF;              // bf16 [N_DST0][512] = 20.5 MB
  u16* agg0b = h0 + (size_t)N_DST0 * NF;              // bf16 [N_DST0][512] = 20.5 MB
  u16* agg1b = agg0b + (size_t)N_DST0 * NF;           // bf16 [N_DST1][512] = 4.2 MB
  float* h1  = (float*)(agg1b + (size_t)N_DST1 * NF); // fp32 [N_DST1][512] = 8.4 MB
  int* ibase    = (int*)(h1 + (size_t)N_DST1 * NF);
  int* cnt_src0 = ibase;
  int* cnt_dst0 = cnt_src0 + N_SRC0;
  int* cnt_src1 = cnt_dst0 + N_DST0;
  int* cnt_dst1 = cnt_src1 + N_DST0;
  int* off0 = cnt_dst1 + N_DST1;
  int* cur0 = off0 + N_DST0 + 1;
  int* csr0 = cur0 + N_DST0;
  int* off1 = csr0 + E0;
  int* cur1 = off1 + N_DST1 + 1;
  int* csr1 = cur1 + N_DST1;
  uint4* wfrag = (uint4*)(((uintptr_t)(csr1 + E1) + 15) & ~(uintptr_t)15);  // 32 KB

  const int NCNT = N_SRC0 + N_DST0 + N_DST0 + N_DST1;
  hipMemsetAsync(cnt_src0, 0, (size_t)NCNT * sizeof(int), stream);

  int tot_cnt = 2 * E0 + 2 * E1;
  k_count4<<<(tot_cnt + 255) / 256, 256, 0, stream>>>(
      e0_src, e0_dst, e1_src, e1_dst, E0, E1, cnt_src0, cnt_dst0, cnt_src1, cnt_dst1);

  k_scan2<<<2, 1024, 0, stream>>>(cnt_dst0, N_DST0, off0, cur0,
                                  cnt_dst1, N_DST1, off1, cur1);

  k_norm<<<(NCNT + 255) / 256, 256, 0, stream>>>(cnt_src0, NCNT);

  k_scatter2<<<(E0 + E1 + 255) / 256, 256, 0, stream>>>(
      e0_src, e0_dst, e1_src, e1_dst, E0, E1, cur0, csr0, cur1, csr1);

  k_wfrag<<<8, 256, 0, stream>>>(W, wfrag);

  dim3 tg1((N_SRC0 + 63) / 64, 4);
  k_transpose_in<<<tg1, 256, 0, stream>>>(in_feat, (const float*)cnt_src0, xp, N_SRC0);

  // layer 0: aggregate (bf16 in/out), then MFMA GEMM -> bf16 h0
  k_agg<<<(N_DST0 + 3) / 4, 256, 0, stream>>>(
      xp, csr0, off0, (const float*)cnt_dst0, agg0b, N_DST0);
  k_gemm_mfma<true><<<(N_DST0 * 4) / 64, 256, 0, stream>>>(
      agg0b, wfrag, bias, (const float*)cnt_src1, (void*)h0, N_DST0 * 4);

  // layer 1: aggregate, MFMA GEMM -> fp32 h1
  k_agg<<<(N_DST1 + 3) / 4, 256, 0, stream>>>(
      h0, csr1, off1, (const float*)cnt_dst1, agg1b, N_DST1);
  k_gemm_mfma<false><<<(N_DST1 * 4) / 64, 256, 0, stream>>>(
      agg1b, wfrag, bias, nullptr, (void*)h1, N_DST1 * 4);

  dim3 tg2(N_DST1 / 64, 4);
  k_transpose_out<<<tg2, 256, 0, stream>>>(h1, (float*)d_out, N_DST1);
}